// Round 1
// baseline (119.560 us; speedup 1.0000x reference)
//
#include <hip/hip_runtime.h>
#include <hip/hip_bf16.h>

// Dilated-mask attention, B=2 H=16 S=2048 D=64, dilation=2 — single fused kernel.
// mask[i,j]=1 iff same parity; masked scores exactly 0 -> flash attn over
// same-parity keys with fixed m=0, Z = l + 1024, out += Vsum_otherparity.
//
// R8: occupancy push. 512 threads / 8 waves per block; wave pair (w, w+4)
// shares the same 32 queries but SPLITS the key tile (kt4 {0,1} vs {2,3}).
// Per-wave LDS tile reads halve, so per-CU LDS traffic is unchanged while
// resident waves double: 8 -> 16 waves/CU (2 blocks x 8 waves, 4/SIMD).
// Staging is spread over 512 threads (per-thread VMEM/cvt halves). Epilogue
// adds a one-time cross-wave O-partial reduction (32 KB LDS, reuses kbuf).

#define B_   2
#define H_   16
#define S_   2048
#define D_   64
#define SP_  1024
#define BQ   128
#define BK   64
#define NKT  (SP_ / BK)
#define NW   8          // waves per block; pair (w, w+4) owns 32 queries

// Q pre-scale: 1/sqrt(64) * log2(e)  ->  p = exp2(QK') = exp(QK/8)
#define QSCALE 0.180336884f

#if __has_builtin(__builtin_amdgcn_exp2f)
#define EXP2(x) __builtin_amdgcn_exp2f(x)
#else
#define EXP2(x) exp2f(x)
#endif

typedef __bf16 bf16x8 __attribute__((ext_vector_type(8)));
typedef __bf16 bf16x4 __attribute__((ext_vector_type(4)));
typedef float  f32x4  __attribute__((ext_vector_type(4)));
typedef short  s16x4  __attribute__((ext_vector_type(4)));

static __device__ __forceinline__ f32x4 mfma16(bf16x4 a, bf16x4 b, f32x4 c) {
    return __builtin_amdgcn_mfma_f32_16x16x16bf16_1k(
        __builtin_bit_cast(s16x4, a), __builtin_bit_cast(s16x4, b), c, 0, 0, 0);
}

// XOR-swizzled element offset inside a 64-elem (128 B) row: 16 B chunk c8 of
// row r lands at chunk c8^(r&7). Staging b128 writes, K b128 frag reads, and
// V^T b64 A-frag reads all <=2-way (free).
#define KSW(r, c8) ((((c8) ^ ((r) & 7)) << 3))

__global__ __launch_bounds__(512, 4) void attn_kernel(const float* __restrict__ Q,
                                                      const float* __restrict__ K,
                                                      const float* __restrict__ V,
                                                      float* __restrict__ out) {
    const int bh  = blockIdx.x;
    const int par = blockIdx.y;
    const int qt  = blockIdx.z;
    const int tid  = threadIdx.x;
    const int lane = tid & 63;
    const int wave = tid >> 6;       // 8 waves
    const int w4   = wave & 3;       // query-group: rows [32*w4, 32*w4+32)
    const int hk   = wave >> 2;      // key half: kt4 in {2*hk, 2*hk+1}
    const int kt4b = hk * 2;
    const int l15  = lane & 15;
    const int quad = lane >> 4;

    // arena layout:
    //   [0,16K)      kbuf[2][64][64] bf16        (epilogue: reused as adump)
    //   [16K,32K)    vbuf[2][64][64] bf16 (V^T)  (epilogue: adump cont.)
    //   [32768,34816) vred[8][64] f32
    //   [34816,36864) lred[4][2][64] f32
    //   [36864,54272) per-lower-wave f32 transpose tiles [16][68]
    __shared__ __align__(16) char arena[54272];
    __bf16 (*kbuf)[BK][64] = (__bf16 (*)[BK][64])arena;
    __bf16 (*vbuf)[D_][64] = (__bf16 (*)[D_][64])(arena + 16384);
    float  (*vred)[64]     = (float  (*)[64])(arena + 32768);
    float  (*lred)[2][64]  = (float  (*)[2][64])(arena + 34816);

    const size_t base = (size_t)bh * S_ * D_;
    const float* Qb = Q + base;
    const float* Kb = K + base;
    const float* Vb = V + base;
    const int vofs = (par == 0) ? D_ : -D_;            // opp-parity row offset

    // ---- Q as QK B-operand fragments (st = K·Q^T): B[n=query l15][k=d]
    bf16x8 qf[2][2];                 // [qt2][ks]
    #pragma unroll
    for (int qt2 = 0; qt2 < 2; ++qt2) {
        const int qrow = qt * BQ + w4 * 32 + qt2 * 16 + l15;
        const float* qsrc = Qb + (size_t)(par + 2 * qrow) * D_ + quad * 8;
        #pragma unroll
        for (int ks = 0; ks < 2; ++ks) {
            const float4 a = *(const float4*)(qsrc + ks * 32);
            const float4 b = *(const float4*)(qsrc + ks * 32 + 4);
            bf16x8 w;
            w[0] = (__bf16)(a.x * QSCALE); w[1] = (__bf16)(a.y * QSCALE);
            w[2] = (__bf16)(a.z * QSCALE); w[3] = (__bf16)(a.w * QSCALE);
            w[4] = (__bf16)(b.x * QSCALE); w[5] = (__bf16)(b.y * QSCALE);
            w[6] = (__bf16)(b.z * QSCALE); w[7] = (__bf16)(b.w * QSCALE);
            qf[qt2][ks] = w;
        }
    }

    // staging decomposition (512 threads):
    //   K: row tid>>3, chunk tid&7 (one b128 each)
    //   V: column d = lane, key-chunk tid>>6 (one b128 each)
    const int kr0 = tid >> 3;
    const int kc8 = tid & 7;
    const int vc  = wave;

    float4 pka, pkb;
    float  pv[8], pvo[8];

    auto issue_loads = [&](int kt) {
        const float* ksrc = Kb + (size_t)(par + 2 * (kt * BK + kr0)) * D_ + kc8 * 8;
        pka = *(const float4*)ksrc;
        pkb = *(const float4*)(ksrc + 4);
        const float* vsrc = Vb + (size_t)(par + 2 * (kt * BK + vc * 8)) * D_ + lane;
        #pragma unroll
        for (int j = 0; j < 8; ++j) {
            pv [j] = vsrc[(size_t)(2 * j) * D_];
            pvo[j] = vsrc[(size_t)(2 * j) * D_ + vofs];
        }
    };

    float vo = 0.f;                  // opp-parity Vsum partial, column d = lane
    auto stage = [&](int buf) {
        bf16x8 w;
        w[0] = (__bf16)pka.x; w[1] = (__bf16)pka.y;
        w[2] = (__bf16)pka.z; w[3] = (__bf16)pka.w;
        w[4] = (__bf16)pkb.x; w[5] = (__bf16)pkb.y;
        w[6] = (__bf16)pkb.z; w[7] = (__bf16)pkb.w;
        *(bf16x8*)&kbuf[buf][kr0][KSW(kr0, kc8)] = w;
        bf16x8 wv;
        #pragma unroll
        for (int j = 0; j < 8; ++j) wv[j] = (__bf16)pv[j];
        *(bf16x8*)&vbuf[buf][lane][KSW(lane, vc)] = wv;
        vo += ((pvo[0] + pvo[1]) + (pvo[2] + pvo[3]))
            + ((pvo[4] + pvo[5]) + (pvo[6] + pvo[7]));
    };

    issue_loads(0);
    stage(0);
    __syncthreads();

    // O^T accumulators: C[m=d=quad*4+r (+16dt)][n=query=l15], per qt2
    // (partial over this wave's key half; cross-wave reduce in epilogue)
    f32x4 acc[2][4];
    #pragma unroll
    for (int q2 = 0; q2 < 2; ++q2)
        #pragma unroll
        for (int dt = 0; dt < 4; ++dt) acc[q2][dt] = (f32x4){0.f, 0.f, 0.f, 0.f};
    float l_acc[2] = {0.f, 0.f};     // per-lane partial Z for query l15 (per qt2)

    for (int kt = 0; kt < NKT; ++kt) {
        const int cur = kt & 1;
        const bool pf = (kt + 1 < NKT);

        if (pf) issue_loads(kt + 1);   // latency overlaps compute below

        const __bf16 (*kb)[64] = kbuf[cur];
        const __bf16 (*vb)[64] = vbuf[cur];

        // ---- K A-fragments for QK (K=32): 4 b128 (this wave's key half)
        bf16x8 ka[2][2];
        #pragma unroll
        for (int ks = 0; ks < 2; ++ks)
            #pragma unroll
            for (int t = 0; t < 2; ++t) {
                const int R = (kt4b + t) * 16 + l15;
                ka[ks][t] = *(const bf16x8*)&kb[R][KSW(R, ks * 4 + quad)];
            }
        // ---- V^T A-fragments for PV (K=16): A[m=d l15][k=key quad*4+j], 8 b64
        bf16x4 va[2][4];             // [t][dt]
        #pragma unroll
        for (int dt = 0; dt < 4; ++dt) {
            const int R = dt * 16 + l15;
            const int ro = R & 7;
            #pragma unroll
            for (int t = 0; t < 2; ++t) {
                const int ch = ((kt4b + t) * 2 + (quad >> 1)) ^ ro;
                va[t][dt] = *(const bf16x4*)&vb[R][ch * 8 + (quad & 1) * 4];
            }
        }

        // ---- st = K·Q^T, p = exp2(st) -> P B-frag in regs -> PV directly
        #pragma unroll
        for (int qt2 = 0; qt2 < 2; ++qt2) {
            f32x4 st[2];
            #pragma unroll
            for (int t = 0; t < 2; ++t) st[t] = (f32x4){0.f, 0.f, 0.f, 0.f};
            #pragma unroll
            for (int ks = 0; ks < 2; ++ks)
                #pragma unroll
                for (int t = 0; t < 2; ++t)
                    st[t] = __builtin_amdgcn_mfma_f32_16x16x32_bf16(
                        ka[ks][t], qf[qt2][ks], st[t], 0, 0, 0);
            #pragma unroll
            for (int t = 0; t < 2; ++t) {
                const float p0 = EXP2(st[t][0]);
                const float p1 = EXP2(st[t][1]);
                const float p2 = EXP2(st[t][2]);
                const float p3 = EXP2(st[t][3]);
                l_acc[qt2] += (p0 + p1) + (p2 + p3);
                bf16x4 pb;
                pb[0] = (__bf16)p0; pb[1] = (__bf16)p1;
                pb[2] = (__bf16)p2; pb[3] = (__bf16)p3;
                #pragma unroll
                for (int dt = 0; dt < 4; ++dt)
                    acc[qt2][dt] = mfma16(va[t][dt], pb, acc[qt2][dt]);
            }
        }

        if (pf) stage(1 - cur);
        __syncthreads();
    }

    // ---- epilogue: cross-wave reductions
    vred[wave][lane] = vo;

    // fold quads: per-lane partial Z for query l15 over this wave's keys
    float lf[2];
    #pragma unroll
    for (int qt2 = 0; qt2 < 2; ++qt2) {
        float Z = l_acc[qt2];
        Z += __shfl_xor(Z, 16);
        Z += __shfl_xor(Z, 32);
        lf[qt2] = Z;
    }

    if (hk) {
        // upper waves: dump partial O^T (reuses kbuf/vbuf region) + partial Z
        f32x4* ad = (f32x4*)(arena + (size_t)w4 * 8192);
        #pragma unroll
        for (int qt2 = 0; qt2 < 2; ++qt2) {
            lred[w4][qt2][lane] = lf[qt2];
            #pragma unroll
            for (int dt = 0; dt < 4; ++dt)
                ad[(qt2 * 4 + dt) * 64 + lane] = acc[qt2][dt];
        }
    }
    __syncthreads();
    if (hk) return;                  // no further barriers below — safe exit

    // lower waves: combine. vso per dt as f32x4 over r (d = dt*16 + quad*4 + r)
    f32x4 vs4[4];
    #pragma unroll
    for (int dt = 0; dt < 4; ++dt) {
        f32x4 s = (f32x4){0.f, 0.f, 0.f, 0.f};
        #pragma unroll
        for (int w = 0; w < NW; ++w)
            s += *(const f32x4*)&vred[w][dt * 16 + quad * 4];
        vs4[dt] = s;
    }
    float rz[2];
    #pragma unroll
    for (int qt2 = 0; qt2 < 2; ++qt2)
        rz[qt2] = 1.0f / (lf[qt2] + lred[w4][qt2][lane] + 1024.0f);

    const f32x4* ad = (const f32x4*)(arena + (size_t)w4 * 8192);

    // ---- epilogue transpose: per-wave private f32 tile [16 q][68 d]
    float* tw = (float*)(arena + 36864) + w4 * (16 * 68);
    #pragma unroll
    for (int qt2 = 0; qt2 < 2; ++qt2) {
        #pragma unroll
        for (int dt = 0; dt < 4; ++dt) {
            const f32x4 o = (acc[qt2][dt] + ad[(qt2 * 4 + dt) * 64 + lane] + vs4[dt])
                          * rz[qt2];
            *(f32x4*)&tw[l15 * 68 + dt * 16 + quad * 4] = o;
        }
        // per-wave private + in-order DS pipe: no barrier needed
        #pragma unroll
        for (int i = 0; i < 4; ++i) {
            const int q = i * 4 + quad;
            const f32x4 ov = *(const f32x4*)&tw[q * 68 + l15 * 4];
            const int qg = par + 2 * (qt * BQ + w4 * 32 + qt2 * 16 + q);
            *(f32x4*)&out[base + (size_t)qg * D_ + l15 * 4] = ov;
        }
    }
}

extern "C" void kernel_launch(void* const* d_in, const int* in_sizes, int n_in,
                              void* d_out, int out_size, void* d_ws, size_t ws_size,
                              hipStream_t stream) {
    const float* Q = (const float*)d_in[0];
    const float* K = (const float*)d_in[1];
    const float* V = (const float*)d_in[2];
    float* out = (float*)d_out;
    attn_kernel<<<dim3(B_ * H_, 2, SP_ / BQ), dim3(512), 0, stream>>>(Q, K, V, out);
}